// Round 1
// baseline (153.009 us; speedup 1.0000x reference)
//
#include <hip/hip_runtime.h>
#include <math.h>

#define KNN 8

__device__ __forceinline__ int lower_bound_i(const int* __restrict__ a, int n, int v) {
  int lo = 0, hi = n;
  while (lo < hi) { int m = (lo + hi) >> 1; if (a[m] < v) lo = m + 1; else hi = m; }
  return lo;
}

// Kernel 1: per-thread query, scan same-batch candidate range, keep sorted top-8.
__global__ void knn_select(const float* __restrict__ x1,
                           const float* __restrict__ x2,
                           const int* __restrict__ b1,
                           const int* __restrict__ b2,
                           int N, int ROW,
                           int* __restrict__ ws_idx,
                           float* __restrict__ ws_w) {
  int q = blockIdx.x * blockDim.x + threadIdx.x;
  if (q >= N) return;
  const float* c2 = x2 + (size_t)q * ROW;
  float qx = c2[0], qy = c2[1], qz = c2[2];
  float n2 = qx * qx + qy * qy + qz * qz;
  int b = b2[q];
  int s1 = lower_bound_i(b1, N, b);
  int e1 = lower_bound_i(b1, N, b + 1);

  float dist[KNN];
  int nidx[KNN];
#pragma unroll
  for (int k = 0; k < KNN; ++k) { dist[k] = INFINITY; nidx[k] = 0; }

  const float* p = x1 + (size_t)s1 * ROW;
  for (int j = s1; j < e1; ++j, p += ROW) {
    float cx = p[0], cy = p[1], cz = p[2];
    float n1 = cx * cx + cy * cy + cz * cz;
    float dt = qx * cx + qy * cy + qz * cz;
    float d = n2 + n1 - 2.0f * dt;
    d = fmaxf(d, 0.0f);
    // strict < : ties keep the earlier (lower) index, matching jax.lax.top_k
    if (d < dist[KNN - 1]) {
      dist[KNN - 1] = d; nidx[KNN - 1] = j;
#pragma unroll
      for (int k = KNN - 1; k > 0; --k) {
        if (dist[k] < dist[k - 1]) {
          float td = dist[k]; dist[k] = dist[k - 1]; dist[k - 1] = td;
          int ti = nidx[k]; nidx[k] = nidx[k - 1]; nidx[k - 1] = ti;
        }
      }
    }
  }
#pragma unroll
  for (int k = 0; k < KNN; ++k) {
    ws_idx[q * KNN + k] = nidx[k];
    // d=inf (padded / <8 candidates) -> w = 1/inf = 0, same as reference
    ws_w[q * KNN + k] = 1.0f / fmaxf(dist[k], 1e-16f);
  }
}

// Kernel 2: one wave (64 lanes) per query; lane l owns feature dims l and l+64.
__global__ void knn_gather_mse(const float* __restrict__ x1,
                               const float* __restrict__ x2,
                               const int* __restrict__ ws_idx,
                               const float* __restrict__ ws_w,
                               int N, int ROW,
                               float* __restrict__ ws_part) {
  int lane = threadIdx.x & 63;
  int wid = threadIdx.x >> 6;
  int q = blockIdx.x * (blockDim.x >> 6) + wid;
  float p = 0.0f;
  if (q < N) {
    float acc0 = 0.0f, acc1 = 0.0f, sumw = 0.0f;
#pragma unroll
    for (int k = 0; k < KNN; ++k) {
      int id = ws_idx[q * KNN + k];
      float w = ws_w[q * KNN + k];
      sumw += w;
      const float* f = x1 + (size_t)id * ROW + 3;
      acc0 += w * f[lane];
      acc1 += w * f[lane + 64];
    }
    const float* f2 = x2 + (size_t)q * ROW + 3;
    float e0 = acc0 / sumw - f2[lane];
    float e1 = acc1 / sumw - f2[lane + 64];
    p = e0 * e0 + e1 * e1;
  }
#pragma unroll
  for (int off = 32; off > 0; off >>= 1) p += __shfl_xor(p, off);
  __shared__ float wsum[8];
  if (lane == 0) wsum[wid] = p;
  __syncthreads();
  if (threadIdx.x == 0) {
    float s = 0.0f;
    int nw = blockDim.x >> 6;
    for (int w = 0; w < nw; ++w) s += wsum[w];
    ws_part[blockIdx.x] = s;
  }
}

// Kernel 3: deterministic final reduction + mean scale.
__global__ void knn_reduce_final(const float* __restrict__ ws_part, int n,
                                 float scale, float* __restrict__ out) {
  __shared__ float sm[256];
  float s = 0.0f;
  for (int i = threadIdx.x; i < n; i += 256) s += ws_part[i];
  sm[threadIdx.x] = s;
  __syncthreads();
  for (int step = 128; step > 0; step >>= 1) {
    if (threadIdx.x < step) sm[threadIdx.x] += sm[threadIdx.x + step];
    __syncthreads();
  }
  if (threadIdx.x == 0) out[0] = sm[0] * scale;
}

extern "C" void kernel_launch(void* const* d_in, const int* in_sizes, int n_in,
                              void* d_out, int out_size, void* d_ws, size_t ws_size,
                              hipStream_t stream) {
  const float* x1 = (const float*)d_in[0];
  const float* x2 = (const float*)d_in[1];
  const int* b1 = (const int*)d_in[2];
  const int* b2 = (const int*)d_in[3];
  int N = in_sizes[2];            // 16384
  int ROW = in_sizes[0] / N;      // 131
  float* out = (float*)d_out;

  int* ws_idx = (int*)d_ws;
  float* ws_w = (float*)((char*)d_ws + (size_t)N * KNN * sizeof(int));
  float* ws_part = (float*)((char*)d_ws + (size_t)N * KNN * (sizeof(int) + sizeof(float)));

  int blocks1 = (N + 255) / 256;
  int blocks2 = (N + 3) / 4;      // 4 waves (queries) per 256-thread block
  size_t need = (size_t)N * KNN * 8 + (size_t)blocks2 * sizeof(float);
  if (ws_size < need) return;     // fail visibly (poisoned d_out) rather than corrupt

  knn_select<<<blocks1, 256, 0, stream>>>(x1, x2, b1, b2, N, ROW, ws_idx, ws_w);
  knn_gather_mse<<<blocks2, 256, 0, stream>>>(x1, x2, ws_idx, ws_w, N, ROW, ws_part);
  float scale = 1.0f / ((float)N * (float)(ROW - 3));
  knn_reduce_final<<<1, 256, 0, stream>>>(ws_part, blocks2, scale, out);
}

// Round 2
// 44.760 us; speedup vs baseline: 3.4184x; 3.4184x over previous
//
#include <hip/hip_runtime.h>
#include <math.h>

#define KNN 8
#define QPB 64          // queries per block
#define SUB 4           // sub-lanes per query
#define BLK (QPB*SUB)   // 256 threads
#define CAP 2048        // staged candidates per LDS tile
#define NBMAX 256       // max batch id capacity

// Kernel 0: batch_starts[b] = first index i with b1[i] >= b (b1 sorted).
__global__ void batch_starts_k(const int* __restrict__ b1, int N,
                               int* __restrict__ starts) {
  int i = blockIdx.x * blockDim.x + threadIdx.x;
  if (i >= N) return;
  int v = b1[i];
  int prev = (i == 0) ? -1 : b1[i - 1];
  for (int b = prev + 1; b <= v; ++b) starts[b] = i;
  if (i == N - 1) { for (int b = v + 1; b <= NBMAX; ++b) starts[b] = N; }
}

// Kernel 1: block stages its queries' candidate coords in LDS (SoA), each
// query is scanned by 4 sub-lanes (stride-4 slices, sorted top-8 each),
// then an exact lexicographic (d, idx) merge across the 4-lane group.
__launch_bounds__(BLK)
__global__ void knn_select(const float* __restrict__ x1,
                           const float* __restrict__ x2,
                           const int* __restrict__ b2,
                           const int* __restrict__ starts,
                           int N, int ROW,
                           int* __restrict__ ws_idx,
                           float* __restrict__ ws_w) {
  __shared__ float xs[CAP], ys[CAP], zs[CAP];
  int tid = threadIdx.x;
  int sub = tid & (SUB - 1);
  int qi  = tid >> 2;
  int q0  = blockIdx.x * QPB;
  int q   = q0 + qi;
  int qlast = min(q0 + QPB - 1, N - 1);

  // block-uniform staging range (b2 sorted => covers all queries in block)
  int s1 = starts[b2[q0]];
  int e1 = starts[b2[qlast] + 1];

  float qx = 0.f, qy = 0.f, qz = 0.f; int qs = 0, qe = 0;
  if (q < N) {
    const float* c2 = x2 + (size_t)q * ROW;
    qx = c2[0]; qy = c2[1]; qz = c2[2];
    int b = b2[q];
    qs = starts[b]; qe = starts[b + 1];
  }
  float n2 = qx * qx + qy * qy + qz * qz;

  float dist[KNN]; int nidx[KNN];
#pragma unroll
  for (int k = 0; k < KNN; ++k) { dist[k] = INFINITY; nidx[k] = 0; }

  for (int t0 = s1; t0 < e1; t0 += CAP) {
    int t1 = min(t0 + CAP, e1);
    __syncthreads();
    for (int i = t0 + tid; i < t1; i += BLK) {
      const float* p = x1 + (size_t)i * ROW;
      int li = i - t0;
      xs[li] = p[0]; ys[li] = p[1]; zs[li] = p[2];
    }
    __syncthreads();
    int lo = max(qs, t0), hi = min(qe, t1);
    int j = qs + sub;
    if (j < lo) j += ((lo - j + SUB - 1) / SUB) * SUB;
    for (; j < hi; j += SUB) {
      int li = j - t0;
      float cx = xs[li], cy = ys[li], cz = zs[li];
      float n1 = cx * cx + cy * cy + cz * cz;
      float dt = qx * cx + qy * cy + qz * cz;
      float d = fmaxf(n2 + n1 - 2.0f * dt, 0.0f);
      // strict < : ascending j => ties keep earlier index within a slice
      if (d < dist[KNN - 1]) {
        dist[KNN - 1] = d; nidx[KNN - 1] = j;
#pragma unroll
        for (int k = KNN - 1; k > 0; --k) {
          if (dist[k] < dist[k - 1]) {
            float td = dist[k]; dist[k] = dist[k - 1]; dist[k - 1] = td;
            int ti = nidx[k]; nidx[k] = nidx[k - 1]; nidx[k - 1] = ti;
          }
        }
      }
    }
  }

  // Exact 4-way merge of sorted lists across lanes 4g..4g+3.
  // Winner each round = lexicographic min over (dist, idx) of the 4 heads.
  float md[KNN]; int mi[KNN];
#pragma unroll
  for (int r = 0; r < KNN; ++r) {
    float hd = dist[0]; int hidx = nidx[0];
    float bd = hd; int bi = hidx;
    float od = __shfl_xor(bd, 1); int oi = __shfl_xor(bi, 1);
    if (od < bd || (od == bd && oi < bi)) { bd = od; bi = oi; }
    od = __shfl_xor(bd, 2); oi = __shfl_xor(bi, 2);
    if (od < bd || (od == bd && oi < bi)) { bd = od; bi = oi; }
    md[r] = bd; mi[r] = bi;
    bool mine = (hd == bd) && (hidx == bi);
    if (mine) {
#pragma unroll
      for (int k = 0; k < KNN - 1; ++k) { dist[k] = dist[k + 1]; nidx[k] = nidx[k + 1]; }
      dist[KNN - 1] = INFINITY; nidx[KNN - 1] = 0;
    }
  }

  if (sub == 0 && q < N) {
#pragma unroll
    for (int r = 0; r < KNN; ++r) {
      ws_idx[q * KNN + r] = mi[r];
      // d=inf (padded) -> w = 0, same as reference's 1/clip(inf)
      ws_w[q * KNN + r] = 1.0f / fmaxf(md[r], 1e-16f);
    }
  }
}

// Kernel 2: one wave per query; lane l owns feature dims l and l+64.
__global__ void knn_gather_mse(const float* __restrict__ x1,
                               const float* __restrict__ x2,
                               const int* __restrict__ ws_idx,
                               const float* __restrict__ ws_w,
                               int N, int ROW,
                               float* __restrict__ ws_part) {
  int lane = threadIdx.x & 63;
  int wid = threadIdx.x >> 6;
  int q = blockIdx.x * (blockDim.x >> 6) + wid;
  float p = 0.0f;
  if (q < N) {
    float acc0 = 0.0f, acc1 = 0.0f, sumw = 0.0f;
#pragma unroll
    for (int k = 0; k < KNN; ++k) {
      int id = ws_idx[q * KNN + k];
      float w = ws_w[q * KNN + k];
      sumw += w;
      const float* f = x1 + (size_t)id * ROW + 3;
      acc0 += w * f[lane];
      acc1 += w * f[lane + 64];
    }
    const float* f2 = x2 + (size_t)q * ROW + 3;
    float e0 = acc0 / sumw - f2[lane];
    float e1 = acc1 / sumw - f2[lane + 64];
    p = e0 * e0 + e1 * e1;
  }
#pragma unroll
  for (int off = 32; off > 0; off >>= 1) p += __shfl_xor(p, off);
  __shared__ float wsum[8];
  if (lane == 0) wsum[wid] = p;
  __syncthreads();
  if (threadIdx.x == 0) {
    float s = 0.0f;
    int nw = blockDim.x >> 6;
    for (int w = 0; w < nw; ++w) s += wsum[w];
    ws_part[blockIdx.x] = s;
  }
}

// Kernel 3: deterministic final reduction + mean scale.
__global__ void knn_reduce_final(const float* __restrict__ ws_part, int n,
                                 float scale, float* __restrict__ out) {
  __shared__ float sm[256];
  float s = 0.0f;
  for (int i = threadIdx.x; i < n; i += 256) s += ws_part[i];
  sm[threadIdx.x] = s;
  __syncthreads();
  for (int step = 128; step > 0; step >>= 1) {
    if (threadIdx.x < step) sm[threadIdx.x] += sm[threadIdx.x + step];
    __syncthreads();
  }
  if (threadIdx.x == 0) out[0] = sm[0] * scale;
}

extern "C" void kernel_launch(void* const* d_in, const int* in_sizes, int n_in,
                              void* d_out, int out_size, void* d_ws, size_t ws_size,
                              hipStream_t stream) {
  const float* x1 = (const float*)d_in[0];
  const float* x2 = (const float*)d_in[1];
  const int* b1 = (const int*)d_in[2];
  const int* b2 = (const int*)d_in[3];
  int N = in_sizes[2];            // 16384
  int ROW = in_sizes[0] / N;      // 131
  float* out = (float*)d_out;

  // ws layout
  char* base = (char*)d_ws;
  int* starts  = (int*)base;                                   // (NBMAX+1) ints, padded to 2048B
  int* ws_idx  = (int*)(base + 2048);                          // N*KNN ints
  float* ws_w  = (float*)(base + 2048 + (size_t)N * KNN * 4);  // N*KNN floats
  float* ws_part = (float*)(base + 2048 + (size_t)N * KNN * 8);

  int blocks0 = (N + 255) / 256;
  int blocks1 = (N + QPB - 1) / QPB;
  int blocks2 = (N + 3) / 4;      // 4 waves (queries) per 256-thread block
  size_t need = 2048 + (size_t)N * KNN * 8 + (size_t)blocks2 * sizeof(float);
  if (ws_size < need) return;     // fail visibly rather than corrupt

  batch_starts_k<<<blocks0, 256, 0, stream>>>(b1, N, starts);
  knn_select<<<blocks1, BLK, 0, stream>>>(x1, x2, b2, starts, N, ROW, ws_idx, ws_w);
  knn_gather_mse<<<blocks2, 256, 0, stream>>>(x1, x2, ws_idx, ws_w, N, ROW, ws_part);
  float scale = 1.0f / ((float)N * (float)(ROW - 3));
  knn_reduce_final<<<1, 256, 0, stream>>>(ws_part, blocks2, scale, out);
}

// Round 3
// 33.005 us; speedup vs baseline: 4.6360x; 1.3562x over previous
//
#include <hip/hip_runtime.h>
#include <math.h>

#define KNN 8
#define QPB 32          // queries per block
#define SUB 8           // sub-lanes per query
#define BLK 256         // QPB*SUB threads
#define CAP 1024        // staged candidates per LDS tile

__device__ __forceinline__ int lbound_g(const int* __restrict__ a, int n, int v) {
  int lo = 0, hi = n;
  while (lo < hi) { int m = (lo + hi) >> 1; if (a[m] < v) lo = m + 1; else hi = m; }
  return lo;
}
__device__ __forceinline__ int lbound_s(const int* a, int n, int v) {
  int lo = 0, hi = n;
  while (lo < hi) { int m = (lo + hi) >> 1; if (a[m] < v) lo = m + 1; else hi = m; }
  return lo;
}

// Fused: stage batch coords in LDS -> 8-way sliced top-8 scan -> exact
// lexicographic (d, idx) merge -> gather features + MSE partial, all in one
// block per 32 queries. One global partial per block (deterministic).
__launch_bounds__(BLK, 2)
__global__ void knn_fused(const float* __restrict__ x1,
                          const float* __restrict__ x2,
                          const int* __restrict__ b1,
                          const int* __restrict__ b2,
                          int N, int ROW,
                          float* __restrict__ ws_part) {
  __shared__ float4 c4[CAP];          // {x, y, z, |c|^2}
  __shared__ int   bs[CAP];           // staged b1 values
  __shared__ int   s_range[2];
  __shared__ int   gi[QPB][KNN];
  __shared__ float gw[QPB][KNN];
  __shared__ float gr[QPB];
  __shared__ float wred[BLK / 64];

  const int tid = threadIdx.x;
  const int qi  = tid >> 3;           // 0..31 query within block
  const int sub = tid & (SUB - 1);    // 0..7 slice
  const int q0  = blockIdx.x * QPB;
  const int q   = q0 + qi;
  const int qlast = min(q0 + QPB - 1, N - 1);

  // block-uniform candidate range: [first of batch b2[q0], end of batch b2[qlast]]
  if (tid < 2) {
    int qq = (tid == 0) ? q0 : qlast;
    int target = b2[qq] + tid;        // tid0: lower_bound(b), tid1: lower_bound(b+1)
    s_range[tid] = lbound_g(b1, N, target);
  }

  float qx = 0.f, qy = 0.f, qz = 0.f; int mybatch = -1;
  if (q < N) {
    const float* c2 = x2 + (size_t)q * ROW;
    qx = c2[0]; qy = c2[1]; qz = c2[2];
    mybatch = b2[q];
  }
  const float n2 = qx * qx + qy * qy + qz * qz;

  float dist[KNN]; int nidx[KNN];
#pragma unroll
  for (int k = 0; k < KNN; ++k) { dist[k] = INFINITY; nidx[k] = 0; }

  __syncthreads();
  const int s1 = s_range[0], e1 = s_range[1];

  for (int t0 = s1; t0 < e1; t0 += CAP) {
    const int t1 = min(t0 + CAP, e1);
    const int L  = t1 - t0;
    __syncthreads();                   // LDS reuse guard (no-op on first tile)
    for (int i = t0 + tid; i < t1; i += BLK) {
      const float* p = x1 + (size_t)i * ROW;
      float cx = p[0], cy = p[1], cz = p[2];
      c4[i - t0] = make_float4(cx, cy, cz, cx * cx + cy * cy + cz * cz);
      bs[i - t0] = b1[i];
    }
    __syncthreads();
    // per-query bounds inside this tile (cheap LDS binary search)
    const int lo = lbound_s(bs, L, mybatch);
    const int hi = lbound_s(bs, L, mybatch + 1);
    for (int j = lo + sub; j < hi; j += SUB) {
      float4 c = c4[j];
      float d = fmaf(-2.0f, qx * c.x + qy * c.y + qz * c.z, n2 + c.w);
      d = fmaxf(d, 0.0f);
      // strict < : ascending j => ties keep earlier index within a slice
      if (d < dist[KNN - 1]) {
        dist[KNN - 1] = d; nidx[KNN - 1] = t0 + j;
#pragma unroll
        for (int k = KNN - 1; k > 0; --k) {
          if (dist[k] < dist[k - 1]) {
            float td = dist[k]; dist[k] = dist[k - 1]; dist[k - 1] = td;
            int ti = nidx[k]; nidx[k] = nidx[k - 1]; nidx[k - 1] = ti;
          }
        }
      }
    }
  }

  // Exact 8-way merge of sorted lists across lanes 8g..8g+7:
  // winner each round = lexicographic min over (dist, idx).
  float md[KNN]; int mi[KNN];
#pragma unroll
  for (int r = 0; r < KNN; ++r) {
    float hd = dist[0]; int hidx = nidx[0];
    float bd = hd; int bi = hidx;
#pragma unroll
    for (int m = 1; m <= 4; m <<= 1) {
      float od = __shfl_xor(bd, m); int oi = __shfl_xor(bi, m);
      if (od < bd || (od == bd && oi < bi)) { bd = od; bi = oi; }
    }
    md[r] = bd; mi[r] = bi;
    if (hd == bd && hidx == bi) {      // unique (d, idx) across slices
#pragma unroll
      for (int k = 0; k < KNN - 1; ++k) { dist[k] = dist[k + 1]; nidx[k] = nidx[k + 1]; }
      dist[KNN - 1] = INFINITY; nidx[KNN - 1] = 0;
    }
  }

  if (sub == 0 && q < N) {
    float sw = 0.0f;
#pragma unroll
    for (int r = 0; r < KNN; ++r) {
      gi[qi][r] = mi[r];
      float w = 1.0f / fmaxf(md[r], 1e-16f);   // d=inf (padded) -> w = 0
      gw[qi][r] = w;
      sw += w;
    }
    gr[qi] = 1.0f / sw;
  }
  __syncthreads();

  // Gather + MSE: 4 waves x 8 queries; lane l owns dims l and l+64.
  const int lane = tid & 63, wv = tid >> 6;
  float p = 0.0f;
  for (int qq = wv * (QPB / 4); qq < (wv + 1) * (QPB / 4); ++qq) {
    int gq = q0 + qq;
    if (gq >= N) break;
    float acc0 = 0.0f, acc1 = 0.0f;
#pragma unroll
    for (int k = 0; k < KNN; ++k) {
      int id = gi[qq][k];
      float w = gw[qq][k];
      const float* f = x1 + (size_t)id * ROW + 3;
      acc0 += w * f[lane];
      acc1 += w * f[lane + 64];
    }
    float r = gr[qq];
    const float* f2 = x2 + (size_t)gq * ROW + 3;
    float e0 = acc0 * r - f2[lane];
    float e1 = acc1 * r - f2[lane + 64];
    p += e0 * e0 + e1 * e1;
  }
#pragma unroll
  for (int off = 32; off > 0; off >>= 1) p += __shfl_xor(p, off);
  if (lane == 0) wred[wv] = p;
  __syncthreads();
  if (tid == 0) {
    float s = 0.0f;
#pragma unroll
    for (int w = 0; w < BLK / 64; ++w) s += wred[w];
    ws_part[blockIdx.x] = s;
  }
}

// Deterministic final reduction + mean scale.
__global__ void knn_final(const float* __restrict__ part, int n,
                          float scale, float* __restrict__ out) {
  __shared__ float sm[256];
  float s = 0.0f;
  for (int i = threadIdx.x; i < n; i += 256) s += part[i];
  sm[threadIdx.x] = s;
  __syncthreads();
  for (int step = 128; step > 0; step >>= 1) {
    if (threadIdx.x < step) sm[threadIdx.x] += sm[threadIdx.x + step];
    __syncthreads();
  }
  if (threadIdx.x == 0) out[0] = sm[0] * scale;
}

extern "C" void kernel_launch(void* const* d_in, const int* in_sizes, int n_in,
                              void* d_out, int out_size, void* d_ws, size_t ws_size,
                              hipStream_t stream) {
  const float* x1 = (const float*)d_in[0];
  const float* x2 = (const float*)d_in[1];
  const int* b1 = (const int*)d_in[2];
  const int* b2 = (const int*)d_in[3];
  int N = in_sizes[2];            // 16384
  int ROW = in_sizes[0] / N;      // 131
  float* out = (float*)d_out;

  int blocks = (N + QPB - 1) / QPB;              // 512
  float* ws_part = (float*)d_ws;
  if (ws_size < (size_t)blocks * sizeof(float)) return;

  knn_fused<<<blocks, BLK, 0, stream>>>(x1, x2, b1, b2, N, ROW, ws_part);
  float scale = 1.0f / ((float)N * (float)(ROW - 3));
  knn_final<<<1, 256, 0, stream>>>(ws_part, blocks, scale, out);
}

// Round 4
// 27.964 us; speedup vs baseline: 5.4716x; 1.1802x over previous
//
#include <hip/hip_runtime.h>
#include <math.h>

#define KNN 8
#define QPB 16          // queries per block
#define SUB 16          // sub-lanes per query
#define BLK 256         // QPB*SUB threads, 4 waves
#define CAP 1024        // staged candidates per LDS tile
#define NBT 258         // batch-id table capacity

// Fused: wave-cooperative range search -> stage coords (+batch tables) in LDS
// -> 16-way sliced top-8 scan -> exact lexicographic (d, idx) shuffle merge
// -> wave-local gather + MSE partial. One deterministic partial per block.
__launch_bounds__(BLK, 4)
__global__ void knn_fused(const float* __restrict__ x1,
                          const float* __restrict__ x2,
                          const int* __restrict__ b1,
                          const int* __restrict__ b2,
                          int N, int ROW,
                          float* __restrict__ ws_part) {
  __shared__ float4 c4[CAP];          // {x, y, z, |c|^2}
  __shared__ int sstart[NBT];         // first in-tile row of batch b
  __shared__ int send[NBT];           // last+1 in-tile row of batch b
  __shared__ int s_range[2];
  __shared__ float wred[BLK / 64];

  const int tid  = threadIdx.x;
  const int lane = tid & 63;
  const int wv   = tid >> 6;
  const int qi   = tid >> 4;          // query within block (SUB=16)
  const int sub  = tid & (SUB - 1);
  const int q0   = blockIdx.x * QPB;
  const int q    = q0 + qi;
  const int qlast = min(q0 + QPB - 1, N - 1);

  // Wave-cooperative lower_bound on b1 (64-way fanout, 3 dependent rounds).
  // Invariant: lb in [lo, hi].
  if (wv < 2) {
    const int target = (wv == 0) ? b2[q0] : (b2[qlast] + 1);
    int lo = 0, hi = N;
    while (lo < hi) {
      int step = (hi - lo + 63) >> 6;
      int p = lo + lane * step;
      bool pred = (p < hi) && (b1[p] < target);
      int c = __popcll(__ballot(pred));
      if (c == 0) { hi = lo; break; }       // lb == lo
      int nlo = lo + (c - 1) * step + 1;
      hi = min(hi, lo + c * step);
      lo = nlo;
    }
    if (lane == 0) s_range[wv] = lo;
  }

  float qx = 0.f, qy = 0.f, qz = 0.f; int mybatch = -1;
  if (q < N) {
    const float* c2 = x2 + (size_t)q * ROW;
    qx = c2[0]; qy = c2[1]; qz = c2[2];
    mybatch = b2[q];
  }
  const float n2 = qx * qx + qy * qy + qz * qz;

  float dist[KNN]; int nidx[KNN];
#pragma unroll
  for (int k = 0; k < KNN; ++k) { dist[k] = INFINITY; nidx[k] = 0; }

  __syncthreads();
  const int s1 = s_range[0], e1 = s_range[1];

  for (int t0 = s1; t0 < e1; t0 += CAP) {
    const int t1 = min(t0 + CAP, e1);
    const int L  = t1 - t0;
    // init batch tables (safe vs. laggard scanners: they only read c4 + regs)
    for (int i = tid; i < NBT; i += BLK) { sstart[i] = CAP; send[i] = 0; }
    __syncthreads();
    // stage coords + build batch boundary tables (unique writer per entry)
    for (int i = t0 + tid; i < t1; i += BLK) {
      const float* p = x1 + (size_t)i * ROW;
      float cx = p[0], cy = p[1], cz = p[2];
      int li = i - t0;
      c4[li] = make_float4(cx, cy, cz, cx * cx + cy * cy + cz * cz);
      int bc = b1[i];
      int bp = (li == 0)     ? (bc ^ 1) : b1[i - 1];
      int bn = (li == L - 1) ? (bc ^ 1) : b1[i + 1];
      if (bc != bp) sstart[bc] = li;
      if (bc != bn) send[bc]  = li + 1;
    }
    __syncthreads();

    int lo = CAP, hi = 0;
    if (mybatch >= 0) { lo = sstart[mybatch]; hi = send[mybatch]; }
    int j = lo + sub;
    if (j < hi) {
      float4 c = c4[j];
      while (true) {
        int jn = j + SUB;
        bool more = jn < hi;
        float4 cn = c4[more ? jn : j];          // harmless clamp, keeps load unconditional
        float d = fmaf(-2.0f, fmaf(qx, c.x, fmaf(qy, c.y, qz * c.z)), n2 + c.w);
        d = fmaxf(d, 0.0f);
        // strict < : ascending j => ties keep earlier index within a slice
        if (d < dist[KNN - 1]) {
          dist[KNN - 1] = d; nidx[KNN - 1] = t0 + j;
#pragma unroll
          for (int k = KNN - 1; k > 0; --k) {
            if (dist[k] < dist[k - 1]) {
              float td = dist[k]; dist[k] = dist[k - 1]; dist[k - 1] = td;
              int ti = nidx[k]; nidx[k] = nidx[k - 1]; nidx[k - 1] = ti;
            }
          }
        }
        if (!more) break;
        j = jn; c = cn;
      }
    }
    // no trailing sync needed: next iteration's table-init doesn't touch c4,
    // and its staging is fenced by the init sync.
  }

  // Exact 16-way merge of sorted lists across each 16-lane group:
  // winner each round = lexicographic min over (dist, idx).
  float md[KNN]; int mi[KNN];
#pragma unroll
  for (int r = 0; r < KNN; ++r) {
    float hd = dist[0]; int hidx = nidx[0];
    float bd = hd; int bi = hidx;
#pragma unroll
    for (int m = 1; m <= 8; m <<= 1) {
      float od = __shfl_xor(bd, m); int oi = __shfl_xor(bi, m);
      if (od < bd || (od == bd && oi < bi)) { bd = od; bi = oi; }
    }
    md[r] = bd; mi[r] = bi;
    if (hd == bd && hidx == bi) {       // unique for real entries; multi-pop of (inf,0) pads is harmless
#pragma unroll
      for (int k = 0; k < KNN - 1; ++k) { dist[k] = dist[k + 1]; nidx[k] = nidx[k + 1]; }
      dist[KNN - 1] = INFINITY; nidx[KNN - 1] = 0;
    }
  }

  // Wave-local gather + MSE: wave wv owns queries q0+4*wv .. +3 (its own groups).
  // Neighbor lists broadcast from lane 16*qq via shfl; lane l owns dims l, l+64.
  float pacc = 0.0f;
#pragma unroll
  for (int qq = 0; qq < 4; ++qq) {
    int gq = q0 + wv * 4 + qq;
    if (gq < N) {                        // wave-uniform branch
      float w[KNN]; int id[KNN]; float sw = 0.0f;
#pragma unroll
      for (int r = 0; r < KNN; ++r) {
        float dd = __shfl(md[r], qq * 16);
        id[r] = __shfl(mi[r], qq * 16);
        w[r] = 1.0f / fmaxf(dd, 1e-16f);  // d=inf (padded) -> w = 0
        sw += w[r];
      }
      float acc0 = 0.0f, acc1 = 0.0f;
#pragma unroll
      for (int r = 0; r < KNN; ++r) {
        const float* f = x1 + (size_t)id[r] * ROW + 3;
        acc0 += w[r] * f[lane];
        acc1 += w[r] * f[lane + 64];
      }
      const float* f2 = x2 + (size_t)gq * ROW + 3;
      float rinv = 1.0f / sw;
      float e0 = acc0 * rinv - f2[lane];
      float e1 = acc1 * rinv - f2[lane + 64];
      pacc += e0 * e0 + e1 * e1;
    }
  }
#pragma unroll
  for (int off = 32; off > 0; off >>= 1) pacc += __shfl_xor(pacc, off);
  if (lane == 0) wred[wv] = pacc;
  __syncthreads();
  if (tid == 0) {
    float s = (wred[0] + wred[1]) + (wred[2] + wred[3]);
    ws_part[blockIdx.x] = s;
  }
}

// Deterministic final reduction + mean scale.
__global__ void knn_final(const float* __restrict__ part, int n,
                          float scale, float* __restrict__ out) {
  __shared__ float sm[256];
  float s = 0.0f;
  for (int i = threadIdx.x; i < n; i += 256) s += part[i];
  sm[threadIdx.x] = s;
  __syncthreads();
  for (int step = 128; step > 0; step >>= 1) {
    if (threadIdx.x < step) sm[threadIdx.x] += sm[threadIdx.x + step];
    __syncthreads();
  }
  if (threadIdx.x == 0) out[0] = sm[0] * scale;
}

extern "C" void kernel_launch(void* const* d_in, const int* in_sizes, int n_in,
                              void* d_out, int out_size, void* d_ws, size_t ws_size,
                              hipStream_t stream) {
  const float* x1 = (const float*)d_in[0];
  const float* x2 = (const float*)d_in[1];
  const int* b1 = (const int*)d_in[2];
  const int* b2 = (const int*)d_in[3];
  int N = in_sizes[2];            // 16384
  int ROW = in_sizes[0] / N;      // 131
  float* out = (float*)d_out;

  int blocks = (N + QPB - 1) / QPB;              // 1024
  float* ws_part = (float*)d_ws;
  if (ws_size < (size_t)blocks * sizeof(float)) return;

  knn_fused<<<blocks, BLK, 0, stream>>>(x1, x2, b1, b2, N, ROW, ws_part);
  float scale = 1.0f / ((float)N * (float)(ROW - 3));
  knn_final<<<1, 256, 0, stream>>>(ws_part, blocks, scale, out);
}